// Round 7
// baseline (12212.904 us; speedup 1.0000x reference)
//
#include <hip/hip_runtime.h>
#include <math.h>

typedef unsigned short u16;

__device__ __forceinline__ float b2f(u16 u) {
    union { unsigned int i; float f; } v; v.i = ((unsigned int)u) << 16; return v.f;
}
__device__ __forceinline__ u16 f2b(float f) {
    union { unsigned int i; float f; } v; v.f = f;
    unsigned int r = v.i + 0x7FFFu + ((v.i >> 16) & 1u);
    return (u16)(r >> 16);
}

// ---- static scratch, runtime-dimensioned (d_ws never used) ----
__device__ __attribute__((aligned(16))) float g_q   [8388608];     // 32 MB  (B,H,S,DK)
__device__ __attribute__((aligned(16))) float g_k   [8388608];     // 32 MB
__device__ __attribute__((aligned(16))) float g_v   [8388608];     // 32 MB
__device__ __attribute__((aligned(16))) u16   g_kedge[134217728];  // 256 MB (B,S,S,DE) bf16
__device__ __attribute__((aligned(16))) float g_ebias[8388608];    // 32 MB  (B,S,S)
__device__ __attribute__((aligned(16))) float g_ctx [8388608];     // 32 MB  (B*S, D)
__device__ __attribute__((aligned(16))) float g_ectx[4194304];     // 16 MB  (B*S, H*DE)
__device__ __attribute__((aligned(16))) float g_z   [8388608];     // 32 MB  (B*S, D)
__device__ int g_isf32;

template<typename T> struct LD;
template<> struct LD<u16> {
    static __device__ __forceinline__ float one(const u16* p, long long i) { return b2f(p[i]); }
};
template<> struct LD<float> {
    static __device__ __forceinline__ float one(const float* p, long long i) { return p[i]; }
};

// bf16 N(0,1) never has exponent >= 0xC0; fp32 low-halves hit it w.p. ~1.
__global__ void detect_k(const void* q) {
    if (threadIdx.x == 0) {
        const u16* p = (const u16*)q;
        int f = 0;
        for (int i = 0; i < 256; i++) {
            int ex = (p[i] >> 7) & 0xFF;
            if (ex >= 0xC0) f = 1;
        }
        g_isf32 = f;
    }
}

__global__ void fill_k(float* out, long long n, float val) {
    long long i = (long long)blockIdx.x * 256 + threadIdx.x;
    if (i < n) out[i] = val;
}

// ---- q/k/v projection: thread per (tok, i); literal ref: out_i = b[i] + sum_j x[j] W[i, j] ----
template<typename T>
__device__ __forceinline__ void proj_body(const T* A, const T* W, const T* bias,
                                          float* out, long long total,
                                          int S, int H, int DK, int D) {
    long long tid = (long long)blockIdx.x * 256 + threadIdx.x;
    if (tid >= total) return;
    long long tok = tid / D;
    int i = (int)(tid % D);
    const T* a = A + tok * D;
    const T* w = W + (long long)i * D;
    float acc = LD<T>::one(bias, i);
    for (int j = 0; j < D; j++)
        acc += LD<T>::one(a, j) * LD<T>::one(w, j);
    long long b = tok / S;
    int s = (int)(tok % S);
    int h = i / DK, d = i % DK;
    out[(((b * H + h) * (long long)S + s)) * DK + d] = acc;
}
__global__ __launch_bounds__(256) void proj_k(const void* A, const void* W,
                                              const void* bias, int which,
                                              long long total, int S, int H,
                                              int DK, int D) {
    float* out = (which == 0) ? g_q : (which == 1) ? g_k : g_v;
    if (g_isf32) proj_body<float>((const float*)A, (const float*)W, (const float*)bias,
                                  out, total, S, H, DK, D);
    else         proj_body<u16>((const u16*)A, (const u16*)W, (const u16*)bias,
                                out, total, S, H, DK, D);
}

// ---- k_edge[bnm, e] = b_Ke[e] + sum_f edge[bnm, f] * W_Ke[e, f] (literal ref) ----
template<typename T>
__device__ __forceinline__ void kedge_body(const T* edge, const T* WKe, const T* bKe,
                                           long long total, int DE) {
    long long tid = (long long)blockIdx.x * 256 + threadIdx.x;
    if (tid >= total) return;
    long long bnm = tid / DE;
    int e = (int)(tid % DE);
    float acc = LD<T>::one(bKe, e);
    const T* er = edge + bnm * DE;
    const T* wr = WKe + (long long)e * DE;
    for (int f = 0; f < DE; f++)
        acc += LD<T>::one(er, f) * LD<T>::one(wr, f);
    g_kedge[tid] = f2b(acc);
}
__global__ __launch_bounds__(256) void kedge_k(const void* edge, const void* WKe,
                                               const void* bKe, long long total, int DE) {
    if (g_isf32) kedge_body<float>((const float*)edge, (const float*)WKe,
                                   (const float*)bKe, total, DE);
    else         kedge_body<u16>((const u16*)edge, (const u16*)WKe,
                                 (const u16*)bKe, total, DE);
}

// ---- edge_bias[bnm] = (b_eb + sum_f edge[bnm,f] * W_eb[f]) / sqrt(2) ----
template<typename T>
__device__ __forceinline__ void ebias_body(const T* edge, const T* Web, const T* beb,
                                           long long total, int DE) {
    long long bnm = (long long)blockIdx.x * 256 + threadIdx.x;
    if (bnm >= total) return;
    float acc = LD<T>::one(beb, 0);
    const T* er = edge + bnm * DE;
    for (int f = 0; f < DE; f++) acc += LD<T>::one(er, f) * LD<T>::one(Web, f);
    g_ebias[bnm] = acc * 0.70710678118654752f;
}
__global__ __launch_bounds__(256) void ebias_k(const void* edge, const void* Web,
                                               const void* beb, long long total, int DE) {
    if (g_isf32) ebias_body<float>((const float*)edge, (const float*)Web,
                                   (const float*)beb, total, DE);
    else         ebias_body<u16>((const u16*)edge, (const u16*)Web,
                                 (const u16*)beb, total, DE);
}

// ---- attention: one block per (b*H + h)*S + n; 256 threads ----
__global__ __launch_bounds__(256) void attn_k(int B, int S, int H, int DK, int DE,
                                              int D, float scale) {
    __shared__ float s_q[128];
    __shared__ float s_attn[2048];
    __shared__ float s_r[4];

    const long long bid = blockIdx.x;
    const int n  = (int)(bid % S);
    const long long bh = bid / S;
    const int h  = (int)(bh % H);
    const long long b = bh / H;
    const int t = threadIdx.x;

    if (t < DK) s_q[t] = g_q[(bh * S + n) * DK + t];
    __syncthreads();

    float lmax = -3.4e38f;
    for (int m = t; m < S; m += 256) {
        const float* kr = g_k + (bh * S + m) * DK;
        float x = 0.f;
        for (int d = 0; d < DK; d++) x += s_q[d] * kr[d];
        x = x * scale + g_ebias[((b * S + n)) * (long long)S + m];
        s_attn[m] = x;
        lmax = fmaxf(lmax, x);
    }
    #pragma unroll
    for (int o = 1; o < 64; o <<= 1) lmax = fmaxf(lmax, __shfl_xor(lmax, o));
    if ((t & 63) == 0) s_r[t >> 6] = lmax;
    __syncthreads();
    const float mx = fmaxf(fmaxf(s_r[0], s_r[1]), fmaxf(s_r[2], s_r[3]));

    float lsum = 0.f;
    for (int m = t; m < S; m += 256) {
        float p = __expf(s_attn[m] - mx);
        s_attn[m] = p;
        lsum += p;
    }
    #pragma unroll
    for (int o = 1; o < 64; o <<= 1) lsum += __shfl_xor(lsum, o);
    __syncthreads();
    if ((t & 63) == 0) s_r[t >> 6] = lsum;
    __syncthreads();
    const float inv = 1.f / (s_r[0] + s_r[1] + s_r[2] + s_r[3]);

    if (t < DK) {
        const float* v0 = g_v + bh * S * DK + t;
        float a = 0.f;
        for (int m = 0; m < S; m++) a += s_attn[m] * v0[(long long)m * DK];
        g_ctx[(b * S + n) * (long long)D + h * DK + t] = a * inv;
    } else if (t - DK < DE) {
        const int e = t - DK;
        const u16* ke = g_kedge + (b * S + n) * (long long)S * DE + e;
        float a = 0.f;
        for (int m = 0; m < S; m++) a += s_attn[m] * b2f(ke[(long long)m * DE]);
        g_ectx[(b * S + n) * (long long)(H * DE) + h * DE + e] = a * inv;
    }
}

// ---- Z[tok, i] = b_eo[i] + sum_c ectx[tok, c] * W_eo[i, c] (literal ref) ----
template<typename T>
__device__ __forceinline__ void zproj_body(const T* Weo, const T* beo,
                                           long long total, int D, int HDE) {
    long long tid = (long long)blockIdx.x * 256 + threadIdx.x;
    if (tid >= total) return;
    long long tok = tid / D;
    int i = (int)(tid % D);
    float acc = LD<T>::one(beo, i);
    const float* ec = g_ectx + tok * HDE;
    const T* wr = Weo + (long long)i * HDE;
    for (int c = 0; c < HDE; c++)
        acc += ec[c] * LD<T>::one(wr, c);
    g_z[tid] = acc;
}
__global__ __launch_bounds__(256) void zproj_k(const void* Weo, const void* beo,
                                               long long total, int D, int HDE) {
    if (g_isf32) zproj_body<float>((const float*)Weo, (const float*)beo, total, D, HDE);
    else         zproj_body<u16>((const u16*)Weo, (const u16*)beo, total, D, HDE);
}

// ---- out[tok,o] = b_o[o] + sum_j ctx[j]*W_o[o,j] + sum_l Z[l]*W_o[o,D+l]; f32 OUTPUT ----
template<typename T>
__device__ __forceinline__ void out_body(const T* Wo, const T* bo, float* out,
                                         long long total, int D) {
    long long tid = (long long)blockIdx.x * 256 + threadIdx.x;
    if (tid >= total) return;
    long long tok = tid / D;
    int o = (int)(tid % D);
    const float* cr = g_ctx + tok * D;
    const float* zr = g_z + tok * D;
    const T* wr = Wo + (long long)o * 2 * D;
    float acc = LD<T>::one(bo, o);
    for (int j = 0; j < D; j++)
        acc += cr[j] * LD<T>::one(wr, j);
    for (int l = 0; l < D; l++)
        acc += zr[l] * LD<T>::one(wr, D + l);
    out[tid] = acc;  // float32 store — d_out is the reference's output dtype (f32)
}
__global__ __launch_bounds__(256) void out_k(const void* Wo, const void* bo, float* out,
                                             long long total, int D) {
    if (g_isf32) out_body<float>((const float*)Wo, (const float*)bo, out, total, D);
    else         out_body<u16>((const u16*)Wo, (const u16*)bo, out, total, D);
}

static inline long long isqrt_ll(long long x) {
    long long r = (long long)(sqrt((double)x) + 0.5);
    return r;
}

extern "C" void kernel_launch(void* const* d_in, const int* in_sizes, int n_in,
                              void* d_out, int out_size, void* d_ws, size_t ws_size,
                              hipStream_t stream)
{
    // inputs are in dict order; edge_embs sits 15 slots before the end
    const int ie = n_in - 15;
    bool ok = (ie >= 1);

    long long D = 0, DE = 0, H = 0, DK = 0, BS = 0, S = 0, B = 0, BSS = 0;
    if (ok) {
        D  = isqrt_ll(in_sizes[ie + 1]);   // W_Q: D*D
        DE = isqrt_ll(in_sizes[ie + 7]);   // W_Ke: DE*DE
        ok = D > 0 && DE > 0 &&
             D * D == (long long)in_sizes[ie + 1] &&
             DE * DE == (long long)in_sizes[ie + 7];
    }
    if (ok) {
        long long weo = in_sizes[ie + 11]; // W_eo: D*DE*H
        H = weo / (D * DE);
        ok = H > 0 && H * D * DE == weo && (D % H) == 0;
        if (ok) DK = D / H;
    }
    if (ok) {
        BS = (long long)in_sizes[0] / D;   // Q: (B,S,D)
        ok = BS > 0 && BS * D == (long long)in_sizes[0];
    }
    if (ok) {
        BSS = (long long)in_sizes[ie] / DE; // edge: (B,S,S,DE)
        ok = BSS * DE == (long long)in_sizes[ie];
        if (ok) { S = BSS / BS; ok = S > 0 && S * BS == BSS; }
        if (ok) { B = BS / S;  ok = B > 0 && B * S == BS; }
    }
    if (ok) {
        ok = 2 * D * D == (long long)in_sizes[ie + 13] &&
             (long long)in_sizes[ie + 2] == D &&
             (long long)in_sizes[ie + 8] == DE &&
             (long long)out_size == BS * D;
    }
    if (ok) {
        ok = BS * D <= 8388608LL && BSS <= 8388608LL &&
             BSS * DE <= 134217728LL && BS * H * DE <= 4194304LL &&
             S <= 2048 && DK <= 128 && DK + DE <= 256;
    }

    if (!ok) {
        long long n = out_size;
        fill_k<<<(int)((n + 255) / 256), 256, 0, stream>>>((float*)d_out, n, 1.0e4f);
        return;
    }

    const void* Q    = d_in[0];
    const void* K    = d_in[1];
    const void* V    = d_in[2];
    const void* edge = d_in[ie];
    const void* W_Q  = d_in[ie + 1];
    const void* b_Q  = d_in[ie + 2];
    const void* W_K  = d_in[ie + 3];
    const void* b_K  = d_in[ie + 4];
    const void* W_V  = d_in[ie + 5];
    const void* b_V  = d_in[ie + 6];
    const void* W_Ke = d_in[ie + 7];
    const void* b_Ke = d_in[ie + 8];
    const void* W_eb = d_in[ie + 9];
    const void* b_eb = d_in[ie + 10];
    const void* W_eo = d_in[ie + 11];
    const void* b_eo = d_in[ie + 12];
    const void* W_o  = d_in[ie + 13];
    const void* b_o  = d_in[ie + 14];

    detect_k<<<1, 64, 0, stream>>>(Q);

    const long long totQKV = BS * D;
    const int gQKV = (int)((totQKV + 255) / 256);
    proj_k<<<gQKV, 256, 0, stream>>>(Q, W_Q, b_Q, 0, totQKV, (int)S, (int)H, (int)DK, (int)D);
    proj_k<<<gQKV, 256, 0, stream>>>(K, W_K, b_K, 1, totQKV, (int)S, (int)H, (int)DK, (int)D);
    proj_k<<<gQKV, 256, 0, stream>>>(V, W_V, b_V, 2, totQKV, (int)S, (int)H, (int)DK, (int)D);

    const long long totKE = BSS * DE;
    kedge_k<<<(int)((totKE + 255) / 256), 256, 0, stream>>>(edge, W_Ke, b_Ke, totKE, (int)DE);
    ebias_k<<<(int)((BSS + 255) / 256), 256, 0, stream>>>(edge, W_eb, b_eb, BSS, (int)DE);

    const float scale = (float)(1.0 / sqrt((double)(2 * DK)));
    attn_k<<<(int)(B * H * S), 256, 0, stream>>>((int)B, (int)S, (int)H, (int)DK,
                                                 (int)DE, (int)D, scale);

    zproj_k<<<gQKV, 256, 0, stream>>>(W_eo, b_eo, totQKV, (int)D, (int)(H * DE));

    out_k<<<gQKV, 256, 0, stream>>>(W_o, b_o, (float*)d_out, totQKV, (int)D);
}